// Round 2
// baseline (432.829 us; speedup 1.0000x reference)
//
#include <hip/hip_runtime.h>

// ResNet theta-step, elementwise closed iteration + scalar fmin reduction.
// x: (4096, 16384) fp32. out: same shape fp32, then one extra float = fmin.
//
// Per element (H=1, THETA=0.5, MAXNITER=10):
//   e   = x + 0.5*relu(x)
//   z0  = e;  z_{k+1} = e + 0.5*relu(z_k)   (10 iterations)
//   out = e + 0.5*relu(z10)
//   r   = z10 - e - 0.5*relu(z10)
//   fmin = 0.5 * sum(r^2)
//
// Memory-bound: 256 MiB in + 256 MiB out, floor ~85 us @ 6.3 TB/s copy ceiling.
// R1 landed pipelined+nontemporal at ~98 us in-kernel (5.5 TB/s effective).
// R2: unroll x2 — two float4 in flight per thread (2 loads + 2 stores
// outstanding, 8 independent z-chains) to close the MLP gap vs a pure copy.
// FP order inside process_one is UNCHANGED (absmax must stay 0.0).

#define THETA 0.5f
#define ONE_MINUS_THETA 0.5f
#define NITER 10

typedef float v4f __attribute__((ext_vector_type(4)));

__device__ __forceinline__ float process_one(float xv, float& acc) {
    float e = xv + ONE_MINUS_THETA * fmaxf(xv, 0.0f);   // H = 1
    float z = e;
#pragma unroll
    for (int it = 0; it < NITER; ++it) {
        z = e + THETA * fmaxf(z, 0.0f);
    }
    float rz = THETA * fmaxf(z, 0.0f);
    float o  = e + rz;
    float r  = z - e - rz;
    acc += 0.5f * r * r;
    return o;
}

__device__ __forceinline__ void process4(const v4f v, v4f& o, float& acc) {
    o.x = process_one(v.x, acc);
    o.y = process_one(v.y, acc);
    o.z = process_one(v.z, acc);
    o.w = process_one(v.w, acc);
}

__global__ __launch_bounds__(256) void resnet_step_kernel(
    const float* __restrict__ x, float* __restrict__ out,
    float* __restrict__ fmin_out, int n4)
{
    const v4f* __restrict__ x4 = (const v4f*)x;
    v4f* __restrict__ o4 = (v4f*)out;

    float local = 0.0f;
    const int stride = gridDim.x * blockDim.x;
    int i = blockIdx.x * blockDim.x + threadIdx.x;

    if (i + stride < n4) {
        // 2-wide software pipeline: two float4 loads in flight across the
        // compute chain; grid-stride pairing keeps both accesses coalesced.
        v4f a = __builtin_nontemporal_load(&x4[i]);
        v4f b = __builtin_nontemporal_load(&x4[i + stride]);
        int cur = i;
        i += 2 * stride;
        for (;;) {
            const bool more = (i + stride < n4);
            v4f an, bn;
            if (more) {
                an = __builtin_nontemporal_load(&x4[i]);           // issue early
                bn = __builtin_nontemporal_load(&x4[i + stride]);
            }

            v4f oa, ob;
            process4(a, oa, local);
            __builtin_nontemporal_store(oa, &o4[cur]);
            process4(b, ob, local);
            __builtin_nontemporal_store(ob, &o4[cur + stride]);

            if (!more) break;
            a = an; b = bn;
            cur = i;
            i += 2 * stride;
        }
        // possible single leftover (not hit at 4096x16384, kept for generality)
        if (i < n4) {
            v4f v = __builtin_nontemporal_load(&x4[i]);
            v4f o;
            process4(v, o, local);
            __builtin_nontemporal_store(o, &o4[i]);
        }
    } else if (i < n4) {
        v4f v = __builtin_nontemporal_load(&x4[i]);
        v4f o;
        process4(v, o, local);
        __builtin_nontemporal_store(o, &o4[i]);
    }

    // wave-64 shuffle reduction
#pragma unroll
    for (int off = 32; off > 0; off >>= 1) {
        local += __shfl_down(local, off, 64);
    }

    __shared__ float s_partial[4];  // 256 threads = 4 waves
    const int lane = threadIdx.x & 63;
    const int wid  = threadIdx.x >> 6;
    if (lane == 0) s_partial[wid] = local;
    __syncthreads();
    if (threadIdx.x == 0) {
        float t = s_partial[0] + s_partial[1] + s_partial[2] + s_partial[3];
        atomicAdd(fmin_out, t);  // device-scope by default on CDNA
    }
}

extern "C" void kernel_launch(void* const* d_in, const int* in_sizes, int n_in,
                              void* d_out, int out_size, void* d_ws, size_t ws_size,
                              hipStream_t stream) {
    const float* x = (const float*)d_in[0];
    float* out = (float*)d_out;
    const int n = in_sizes[0];          // 4096*16384 = 67108864 (divisible by 4)
    float* fmin_out = out + n;          // out_size = n + 1

    // d_out is re-poisoned to 0xAA before every timed replay — zero the
    // accumulator slot ourselves (async memset is graph-capture legal).
    hipMemsetAsync(fmin_out, 0, sizeof(float), stream);

    const int n4 = n / 4;
    dim3 block(256);
    dim3 grid(2048);                    // 8 blocks/CU * 256 CUs = 32 waves/CU
    resnet_step_kernel<<<grid, block, 0, stream>>>(x, out, fmin_out, n4);
}